// Round 5
// baseline (161.698 us; speedup 1.0000x reference)
//
#include <hip/hip_runtime.h>
#include <cmath>

typedef __attribute__((ext_vector_type(8))) short short8;
typedef __attribute__((ext_vector_type(4))) float f32x4;

#define ALPHA_ 0.2f
#define NEGINF (-9.0e15f)

__device__ __forceinline__ ushort f2b(float f) {
    union { float f; unsigned u; } v; v.f = f;
    unsigned r = v.u + 0x7fffu + ((v.u >> 16) & 1u);
    return (ushort)(r >> 16);
}

// ---------------------------------------------------------------------------
// prep (grid 200 x 256):
//  - adjb[i][0..7]: bitmask of adj row i (bit j%32 of dword j/32), j>=200 -> 0
//  - WT1[64][320], WT2[64][64]: transposed bf16 weights
//  - wv1[4][320] = {W10@a10_src, W10@a10_dst, W11@a11_src, W11@a11_dst} (f32)
//  - wv2[2][64]  = {W2@a2_src, W2@a2_dst} (f32)
//  - HT pad columns [200,224) zeroed for all 256*64 feature rows
// ---------------------------------------------------------------------------
__global__ __launch_bounds__(256) void prep_kernel(
    const int* __restrict__ adj, const float* __restrict__ W10,
    const float* __restrict__ W11, const float* __restrict__ W2,
    const float* __restrict__ a10, const float* __restrict__ a11,
    const float* __restrict__ a2,
    unsigned* __restrict__ adjb, ushort* __restrict__ WT1,
    ushort* __restrict__ WT2, float* __restrict__ wv1,
    float* __restrict__ wv2, ushort* __restrict__ HT)
{
    const int bx = blockIdx.x, tid = threadIdx.x;
    if (tid < 8) {
        unsigned mask = 0;
        for (int u = 0; u < 32; ++u) {
            const int j = tid * 32 + u;
            if (j < 200 && adj[bx * 200 + j] > 0) mask |= (1u << u);
        }
        adjb[bx * 8 + tid] = mask;
    }
    const int gidx = bx * 256 + tid;                 // 0..51199
    if (gidx < 64 * 320) {
        const int n = gidx / 320, k = gidx % 320;
        WT1[gidx] = f2b(n < 32 ? W10[k * 32 + n] : W11[k * 32 + (n - 32)]);
    }
    if (gidx < 64 * 64) {
        const int n = gidx >> 6, k = gidx & 63;
        WT2[gidx] = f2b(W2[k * 64 + n]);
    }
    if (gidx < 1280) {                               // wv1
        const int k = gidx >> 2, q = gidx & 3;
        const float* Wp = (q < 2) ? (W10 + k * 32) : (W11 + k * 32);
        const float* av = ((q < 2) ? a10 : a11) + (q & 1) * 32;
        float s = 0.f;
        for (int f = 0; f < 32; ++f) s += Wp[f] * av[f];
        wv1[q * 320 + k] = s;
    }
    if (gidx < 128) {                                // wv2
        const int k = gidx >> 1, q = gidx & 1;
        float s = 0.f;
        for (int f = 0; f < 64; ++f) s += W2[k * 64 + f] * a2[q * 64 + f];
        wv2[q * 64 + k] = s;
    }
    if (gidx < 256 * 64 * 3) {                       // HT pad zero (3 x uint4 per row)
        const int c = gidx % 3, bf = gidx / 3;
        uint4 z{0, 0, 0, 0};
        *(uint4*)&HT[(size_t)bf * 224 + 200 + c * 8] = z;
    }
}

// ---------------------------------------------------------------------------
// sd1: per global row i, sd1[i][4] = {src_h0, dst_h0, src_h1, dst_h1}
// ---------------------------------------------------------------------------
__global__ __launch_bounds__(256) void sd1_kernel(const float* __restrict__ x,
                                                  const float* __restrict__ wv1,
                                                  float* __restrict__ sd1)
{
    __shared__ __attribute__((aligned(16))) float wl[4 * 320];
    const int tid = threadIdx.x;
    for (int i = tid; i < 1280; i += 256) wl[i] = wv1[i];
    __syncthreads();
    const int lane = tid & 63, w = tid >> 6;
    const size_t row = (size_t)blockIdx.x * 4 + w;
    float a0 = 0.f, a1 = 0.f, a2v = 0.f, a3 = 0.f;
    #pragma unroll
    for (int c = 0; c < 5; ++c) {
        const float xv = x[row * 320 + c * 64 + lane];
        const int k = c * 64 + lane;
        a0 += xv * wl[k]; a1 += xv * wl[320 + k];
        a2v += xv * wl[640 + k]; a3 += xv * wl[960 + k];
    }
    #pragma unroll
    for (int s = 1; s < 64; s <<= 1) {
        a0 += __shfl_xor(a0, s, 64); a1 += __shfl_xor(a1, s, 64);
        a2v += __shfl_xor(a2v, s, 64); a3 += __shfl_xor(a3, s, 64);
    }
    if (lane == 0) {
        float4 o; o.x = a0; o.y = a1; o.z = a2v; o.w = a3;
        *(float4*)&sd1[row * 4] = o;
    }
}

// sd2: sd2[i][2] = dot(x1[i, 0:64], wv2[q]); x1 = out cols 0..63 (stride 128)
__global__ __launch_bounds__(256) void sd2_kernel(const float* __restrict__ x1,
                                                  const float* __restrict__ wv2,
                                                  float* __restrict__ sd2)
{
    __shared__ __attribute__((aligned(16))) float wl[128];
    const int tid = threadIdx.x;
    if (tid < 128) wl[tid] = wv2[tid];
    __syncthreads();
    const int lane = tid & 63, w = tid >> 6;
    const size_t row = (size_t)blockIdx.x * 4 + w;
    const float v = x1[row * 128 + lane];
    float a0 = v * wl[lane], a1 = v * wl[64 + lane];
    #pragma unroll
    for (int s = 1; s < 64; s <<= 1) {
        a0 += __shfl_xor(a0, s, 64); a1 += __shfl_xor(a1, s, 64);
    }
    if (lane == 0) {
        float2 o; o.x = a0; o.y = a1;
        *(float2*)&sd2[row * 2] = o;
    }
}

// ---------------------------------------------------------------------------
// gemm: HT[b][f][jpad224] (bf16) = X[51200 x K] @ W[K x 64]
// ---------------------------------------------------------------------------
template<int K, int LDX>
__global__ __launch_bounds__(256) void gemm_mfma(const float* __restrict__ X,
                                                 const ushort* __restrict__ WT,
                                                 ushort* __restrict__ HT)
{
    constexpr int KP = K + 8;
    __shared__ __attribute__((aligned(16))) ushort wt_lds[64][KP];
    const int tid = threadIdx.x;
    constexpr int CH = 64 * (K / 8);
    for (int c = tid; c < CH; c += 256) {
        int n = c / (K / 8), kc = (c % (K / 8)) * 8;
        *(short8*)&wt_lds[n][kc] = *(const short8*)&WT[n * K + kc];
    }
    __syncthreads();

    const int lane = tid & 63, w = tid >> 6;
    const int m = lane & 15, g = lane >> 4;
    const int ko = g * 8;
    const size_t row = (size_t)blockIdx.x * 64 + w * 16 + m;

    f32x4 acc[4] = {{0,0,0,0},{0,0,0,0},{0,0,0,0},{0,0,0,0}};
    #pragma unroll
    for (int k0 = 0; k0 < K; k0 += 32) {
        const float4 x0 = *(const float4*)&X[row * LDX + k0 + ko];
        const float4 x1 = *(const float4*)&X[row * LDX + k0 + ko + 4];
        short8 a;
        a[0] = (short)f2b(x0.x); a[1] = (short)f2b(x0.y);
        a[2] = (short)f2b(x0.z); a[3] = (short)f2b(x0.w);
        a[4] = (short)f2b(x1.x); a[5] = (short)f2b(x1.y);
        a[6] = (short)f2b(x1.z); a[7] = (short)f2b(x1.w);
        #pragma unroll
        for (int nt = 0; nt < 4; ++nt) {
            const short8 bfr = *(const short8*)&wt_lds[nt * 16 + m][k0 + ko];
            acc[nt] = __builtin_amdgcn_mfma_f32_16x16x32_bf16(a, bfr, acc[nt], 0, 0, 0);
        }
    }

    const unsigned rb = (unsigned)blockIdx.x * 64 + w * 16 + g * 4;  // 4 | 200
    const unsigned bt = rb / 200u;
    const unsigned ir = rb - bt * 200u;
    #pragma unroll
    for (int nt = 0; nt < 4; ++nt) {
        uint2 pk;
        pk.x = (unsigned)f2b(acc[nt][0]) | ((unsigned)f2b(acc[nt][1]) << 16);
        pk.y = (unsigned)f2b(acc[nt][2]) | ((unsigned)f2b(acc[nt][3]) << 16);
        *(uint2*)&HT[((size_t)bt * 64 + nt * 16 + m) * 224 + ir] = pk;
    }
}

// ---------------------------------------------------------------------------
// Fused GAT attention, single-pass no-max softmax.
// Lane (m = lane&15, g = lane>>4) owns softmax row i0+m, j-slice
// {ks*32 + g*8 + u}.  No max pass: e bounded (~|40| max), clamp 80 as
// overflow insurance; masked -> NEGINF -> exp = 0.  Row-sum reduce =
// 2 shfl_xor; inv distributed via __shfl (no LDS).
// MODE 0: bx = ((b*2+head)*2+sub), sub in {0,1}: tiles 0..6 / 7..12. F=32.
// MODE 1: bx = b*4+sub, sub in {0..3}: tiles {0-3,4-6,7-9,10-12}. F=64.
// ---------------------------------------------------------------------------
template<int F, int MODE>
__global__ __launch_bounds__(256, 4) void attn_mfma(const ushort* __restrict__ HT,
                                                    const unsigned* __restrict__ adjb,
                                                    const float* __restrict__ sd,
                                                    float* __restrict__ out)
{
    __shared__ __attribute__((aligned(16))) ushort hT[F][232];
    __shared__ __attribute__((aligned(16))) float src_l[224];
    __shared__ __attribute__((aligned(16))) float dst_l[224];
    __shared__ unsigned adjl[208][9];   // pad 9 -> conflict-free row reads

    const int tid = threadIdx.x;
    const int lane = tid & 63, w = tid >> 6;
    const int bx = blockIdx.x;
    int b, hoff, outc0, head, tA, tB;
    if (MODE == 0) {
        b = bx >> 2; head = (bx >> 1) & 1; const int sub = bx & 1;
        hoff = head * 32; outc0 = head * 32;
        tA = sub ? 7 : 0; tB = sub ? 13 : 7;
    } else {
        b = bx >> 2; head = 0; const int sub = bx & 3;
        hoff = 0; outc0 = 64;
        tA = (sub == 0) ? 0 : 4 + (sub - 1) * 3;
        tB = (sub == 0) ? 4 : tA + 3;
    }

    // stage hT (coalesced short8)
    const ushort* hg = HT + ((size_t)b * 64 + hoff) * 224;
    for (int idx = tid; idx < F * 28; idx += 256) {
        const int f = idx / 28, c = idx % 28;
        *(short8*)&hT[f][c * 8] = *(const short8*)&hg[(size_t)f * 224 + c * 8];
    }
    // stage adj bitmasks (rows 200..207 zero; col 8 = pad, unwritten)
    for (int idx = tid; idx < 208 * 8; idx += 256) {
        const int i = idx >> 3, c = idx & 7;
        adjl[i][c] = (i < 200) ? adjb[i * 8 + c] : 0u;
    }
    // stage src/dst (f32-exact from sd tables)
    if (tid < 224) {
        float s = 0.f, d = 0.f;
        if (tid < 200) {
            if (MODE == 0) {
                const float4 q4 = *(const float4*)&sd[(size_t)(b * 200 + tid) * 4];
                s = head ? q4.z : q4.x;
                d = head ? q4.w : q4.y;
            } else {
                const float2 q2 = *(const float2*)&sd[(size_t)(b * 200 + tid) * 2];
                s = q2.x; d = q2.y;
            }
        }
        src_l[tid] = s; dst_l[tid] = d;
    }
    __syncthreads();

    const int m = lane & 15, g = lane >> 4;

    for (int t = tA + w; t < tB; t += 4) {
        const int i0 = t * 16;
        const int isf = i0 + m;
        const float si = src_l[isf];

        float s0 = 0.f, s1 = 0.f, s2 = 0.f, s3 = 0.f;
        short8 af[7];
        #pragma unroll
        for (int ks = 0; ks < 7; ++ks) {
            const unsigned bits = (adjl[isf][ks] >> (g * 8)) & 0xffu;
            const float4 d0 = *(const float4*)&dst_l[ks * 32 + g * 8];
            const float4 d1 = *(const float4*)&dst_l[ks * 32 + g * 8 + 4];
            const float dvv[8] = {d0.x, d0.y, d0.z, d0.w, d1.x, d1.y, d1.z, d1.w};
            float p[8];
            #pragma unroll
            for (int u = 0; u < 8; ++u) {
                float v = si + dvv[u];
                v = fmaxf(v, ALPHA_ * v);                       // leaky-relu
                const float e = ((bits >> u) & 1u) ? v : NEGINF;
                p[u] = __expf(fminf(e, 80.f));                  // overflow guard only
                af[ks][u] = (short)f2b(p[u]);
            }
            s0 += p[0] + p[4]; s1 += p[1] + p[5];
            s2 += p[2] + p[6]; s3 += p[3] + p[7];
        }
        float sum = (s0 + s1) + (s2 + s3);
        sum += __shfl_xor(sum, 16, 64);
        sum += __shfl_xor(sum, 32, 64);
        const float inv = 1.f / sum;   // row-m inverse, valid in all (m,*) lanes

        #pragma unroll
        for (int nt = 0; nt < F / 16; ++nt) {
            f32x4 acc = {0, 0, 0, 0};
            #pragma unroll
            for (int ks = 0; ks < 7; ++ks) {
                const short8 bf = *(const short8*)&hT[nt * 16 + m][ks * 32 + g * 8];
                acc = __builtin_amdgcn_mfma_f32_16x16x32_bf16(af[ks], bf, acc, 0, 0, 0);
            }
            #pragma unroll
            for (int r = 0; r < 4; ++r) {
                const int row = g * 4 + r;
                const int ii = i0 + row;
                const float invr = __shfl(inv, row, 64);  // from lane m'=row, g'=0
                if (ii < 200) {
                    float vv = acc[r] * invr;
                    vv = (vv > 0.f) ? vv : expm1f(vv);
                    out[((size_t)b * 200 + ii) * 128 + outc0 + nt * 16 + m] = vv;
                }
            }
        }
    }
}

extern "C" void kernel_launch(void* const* d_in, const int* in_sizes, int n_in,
                              void* d_out, int out_size, void* d_ws, size_t ws_size,
                              hipStream_t stream)
{
    const float* x   = (const float*)d_in[0];
    const int*   adj = (const int*)  d_in[1];
    const float* W10 = (const float*)d_in[2];
    const float* a10 = (const float*)d_in[3];
    const float* W11 = (const float*)d_in[4];
    const float* a11 = (const float*)d_in[5];
    const float* W2  = (const float*)d_in[6];
    const float* a2  = (const float*)d_in[7];
    float* out = (float*)d_out;

    char* ws = (char*)d_ws;
    ushort*   HT   = (ushort*)  ws;                  // 7,340,032 B
    ushort*   WT1  = (ushort*) (ws + 7340032);       //    40,960 B
    ushort*   WT2  = (ushort*) (ws + 7380992);       //     8,192 B
    unsigned* adjb = (unsigned*)(ws + 7389184);      //     6,400 B
    float*    wv1  = (float*)  (ws + 7395584);       //     5,120 B
    float*    wv2  = (float*)  (ws + 7400704);       //       512 B
    float*    sd1  = (float*)  (ws + 7401216);       //   819,200 B
    float*    sd2  = (float*)  (ws + 8220416);       //   409,600 B  (total 8.63 MB)

    prep_kernel<<<200, 256, 0, stream>>>(adj, W10, W11, W2, a10, a11, a2,
                                         adjb, WT1, WT2, wv1, wv2, HT);
    sd1_kernel<<<12800, 256, 0, stream>>>(x, wv1, sd1);
    gemm_mfma<320, 320><<<800, 256, 0, stream>>>(x, WT1, HT);
    attn_mfma<32, 0><<<1024, 256, 0, stream>>>(HT, adjb, sd1, out);
    sd2_kernel<<<12800, 256, 0, stream>>>(out, wv2, sd2);
    gemm_mfma<64, 128><<<800, 256, 0, stream>>>(out, WT2, HT);
    attn_mfma<64, 1><<<1024, 256, 0, stream>>>(HT, adjb, sd2, out);
}

// Round 6
// 84.547 us; speedup vs baseline: 1.9125x; 1.9125x over previous
//
#include <hip/hip_runtime.h>
#include <cmath>

typedef __attribute__((ext_vector_type(8))) short short8;
typedef __attribute__((ext_vector_type(4))) float f32x4;

#define ALPHA_ 0.2f
#define NEGINF (-9.0e15f)

__device__ __forceinline__ ushort f2b(float f) {
    union { float f; unsigned u; } v; v.f = f;
    unsigned r = v.u + 0x7fffu + ((v.u >> 16) & 1u);
    return (ushort)(r >> 16);
}

// ---------------------------------------------------------------------------
// prep (grid 200 x 256):
//  - adjb[i][0..7]: bitmask of adj row i (bit j%32 of dword j/32), j>=200 -> 0
//  - WT1[64][320], WT2[64][64]: transposed bf16 weights
//  - AC1[4][64]: coefficient table for layer-1 src/dst fused dots:
//      q0 = a10_src (cols 0..31), q1 = a10_dst, q2 = a11_src (cols 32..63),
//      q3 = a11_dst; zero outside the head's column range.
//  - HT pad columns [200,224) zeroed for all 256*64 feature rows
// ---------------------------------------------------------------------------
__global__ __launch_bounds__(256) void prep_kernel(
    const int* __restrict__ adj, const float* __restrict__ W10,
    const float* __restrict__ W11, const float* __restrict__ W2,
    const float* __restrict__ a10, const float* __restrict__ a11,
    unsigned* __restrict__ adjb, ushort* __restrict__ WT1,
    ushort* __restrict__ WT2, float* __restrict__ AC1,
    ushort* __restrict__ HT)
{
    const int bx = blockIdx.x, tid = threadIdx.x;
    if (tid < 8) {
        unsigned mask = 0;
        for (int u = 0; u < 32; ++u) {
            const int j = tid * 32 + u;
            if (j < 200 && adj[bx * 200 + j] > 0) mask |= (1u << u);
        }
        adjb[bx * 8 + tid] = mask;
    }
    const int gidx = bx * 256 + tid;                 // 0..51199
    if (gidx < 64 * 320) {
        const int n = gidx / 320, k = gidx % 320;
        WT1[gidx] = f2b(n < 32 ? W10[k * 32 + n] : W11[k * 32 + (n - 32)]);
    }
    if (gidx < 64 * 64) {
        const int n = gidx >> 6, k = gidx & 63;
        WT2[gidx] = f2b(W2[k * 64 + n]);
    }
    if (gidx < 256) {                                // AC1
        const int q = gidx >> 6, f = gidx & 63;
        float v = 0.f;
        if (q == 0 && f < 32)  v = a10[f];
        if (q == 1 && f < 32)  v = a10[32 + f];
        if (q == 2 && f >= 32) v = a11[f - 32];
        if (q == 3 && f >= 32) v = a11[f];           // a11[32 + (f-32)]
        AC1[gidx] = v;
    }
    if (gidx < 256 * 64 * 3) {                       // HT pad zero (3 x uint4 per row)
        const int c = gidx % 3, bf = gidx / 3;
        uint4 z{0, 0, 0, 0};
        *(uint4*)&HT[(size_t)bf * 224 + 200 + c * 8] = z;
    }
}

// ---------------------------------------------------------------------------
// gemm + fused src/dst dots:
//   HT[b][f][jpad224] (bf16) = X[51200 x K] @ W[K x 64]
//   SD[row][q] = sum_f acc[row][f] * AC[q][f]   (f32, from accumulators)
// ---------------------------------------------------------------------------
template<int K, int LDX, int NSD>
__global__ __launch_bounds__(256) void gemm_mfma(const float* __restrict__ X,
                                                 const ushort* __restrict__ WT,
                                                 const float* __restrict__ AC,
                                                 ushort* __restrict__ HT,
                                                 float* __restrict__ SD)
{
    constexpr int KP = K + 8;
    __shared__ __attribute__((aligned(16))) ushort wt_lds[64][KP];
    __shared__ __attribute__((aligned(16))) float acl[NSD * 64];
    const int tid = threadIdx.x;
    constexpr int CH = 64 * (K / 8);
    for (int c = tid; c < CH; c += 256) {
        int n = c / (K / 8), kc = (c % (K / 8)) * 8;
        *(short8*)&wt_lds[n][kc] = *(const short8*)&WT[n * K + kc];
    }
    if (tid < NSD * 64) acl[tid] = AC[tid];
    __syncthreads();

    const int lane = tid & 63, w = tid >> 6;
    const int m = lane & 15, g = lane >> 4;
    const int ko = g * 8;
    const size_t row = (size_t)blockIdx.x * 64 + w * 16 + m;

    f32x4 acc[4] = {{0,0,0,0},{0,0,0,0},{0,0,0,0},{0,0,0,0}};
    #pragma unroll
    for (int k0 = 0; k0 < K; k0 += 32) {
        const float4 x0 = *(const float4*)&X[row * LDX + k0 + ko];
        const float4 x1 = *(const float4*)&X[row * LDX + k0 + ko + 4];
        short8 a;
        a[0] = (short)f2b(x0.x); a[1] = (short)f2b(x0.y);
        a[2] = (short)f2b(x0.z); a[3] = (short)f2b(x0.w);
        a[4] = (short)f2b(x1.x); a[5] = (short)f2b(x1.y);
        a[6] = (short)f2b(x1.z); a[7] = (short)f2b(x1.w);
        #pragma unroll
        for (int nt = 0; nt < 4; ++nt) {
            const short8 bfr = *(const short8*)&wt_lds[nt * 16 + m][k0 + ko];
            acc[nt] = __builtin_amdgcn_mfma_f32_16x16x32_bf16(a, bfr, acc[nt], 0, 0, 0);
        }
    }

    // HT store (bf16 packed), rows rb..rb+3 (4 | 200 -> never straddles batch)
    const unsigned rb = (unsigned)blockIdx.x * 64 + w * 16 + g * 4;
    const unsigned bt = rb / 200u;
    const unsigned ir = rb - bt * 200u;
    #pragma unroll
    for (int nt = 0; nt < 4; ++nt) {
        uint2 pk;
        pk.x = (unsigned)f2b(acc[nt][0]) | ((unsigned)f2b(acc[nt][1]) << 16);
        pk.y = (unsigned)f2b(acc[nt][2]) | ((unsigned)f2b(acc[nt][3]) << 16);
        *(uint2*)&HT[((size_t)bt * 64 + nt * 16 + m) * 224 + ir] = pk;
    }

    // fused src/dst dots from f32 accumulators
    float sdv[NSD][4];
    #pragma unroll
    for (int q = 0; q < NSD; ++q)
        #pragma unroll
        for (int r = 0; r < 4; ++r) {
            float s = 0.f;
            #pragma unroll
            for (int nt = 0; nt < 4; ++nt) s += acc[nt][r] * acl[q * 64 + nt * 16 + m];
            sdv[q][r] = s;
        }
    #pragma unroll
    for (int q = 0; q < NSD; ++q)
        #pragma unroll
        for (int r = 0; r < 4; ++r) {
            float s = sdv[q][r];
            s += __shfl_xor(s, 1, 64); s += __shfl_xor(s, 2, 64);
            s += __shfl_xor(s, 4, 64); s += __shfl_xor(s, 8, 64);
            sdv[q][r] = s;
        }
    if (m == 0) {
        #pragma unroll
        for (int r = 0; r < 4; ++r) {
            if (NSD == 4) {
                float4 o; o.x = sdv[0][r]; o.y = sdv[1][r];
                o.z = sdv[2][r]; o.w = sdv[3][r];
                *(float4*)&SD[(size_t)(rb + r) * 4] = o;
            } else {
                float2 o; o.x = sdv[0][r]; o.y = sdv[1][r];
                *(float2*)&SD[(size_t)(rb + r) * 2] = o;
            }
        }
    }
}

// ---------------------------------------------------------------------------
// Fused GAT attention, single-pass no-max softmax, ks-outer PV (one A-frag
// live at a time).  Lane (m = lane&15, g = lane>>4) owns softmax row i0+m,
// j-slice {ks*32 + g*8 + u}.  Masked -> NEGINF -> exp = 0; clamp 80 is
// overflow insurance only (|e| bounded ~25 by input statistics).
// MODE 0: bx = ((b*2+head)*2+sub), sub {0,1}: tiles 0..6 / 7..12. F=32.
// MODE 1: bx = b*4+sub, sub {0..3}: tiles {0-3,4-6,7-9,10-12}. F=64.
// ---------------------------------------------------------------------------
template<int F, int MODE>
__global__ __launch_bounds__(256) void attn_mfma(const ushort* __restrict__ HT,
                                                 const unsigned* __restrict__ adjb,
                                                 const float* __restrict__ sd,
                                                 float* __restrict__ out)
{
    __shared__ __attribute__((aligned(16))) ushort hT[F][232];
    __shared__ __attribute__((aligned(16))) float src_l[224];
    __shared__ __attribute__((aligned(16))) float dst_l[224];
    __shared__ unsigned adjl[208][9];   // pad 9 -> conflict-free row reads

    const int tid = threadIdx.x;
    const int lane = tid & 63, w = tid >> 6;
    const int bx = blockIdx.x;
    int b, hoff, outc0, head, tA, tB;
    if (MODE == 0) {
        b = bx >> 2; head = (bx >> 1) & 1; const int sub = bx & 1;
        hoff = head * 32; outc0 = head * 32;
        tA = sub ? 7 : 0; tB = sub ? 13 : 7;
    } else {
        b = bx >> 2; head = 0; const int sub = bx & 3;
        hoff = 0; outc0 = 64;
        tA = (sub == 0) ? 0 : 4 + (sub - 1) * 3;
        tB = (sub == 0) ? 4 : tA + 3;
    }

    // stage hT (coalesced short8)
    const ushort* hg = HT + ((size_t)b * 64 + hoff) * 224;
    for (int idx = tid; idx < F * 28; idx += 256) {
        const int f = idx / 28, c = idx % 28;
        *(short8*)&hT[f][c * 8] = *(const short8*)&hg[(size_t)f * 224 + c * 8];
    }
    // stage adj bitmasks (rows 200..207 zero; col 8 = pad, unwritten)
    for (int idx = tid; idx < 208 * 8; idx += 256) {
        const int i = idx >> 3, c = idx & 7;
        adjl[i][c] = (i < 200) ? adjb[i * 8 + c] : 0u;
    }
    // stage src/dst (f32 from fused gemm epilogue tables)
    if (tid < 224) {
        float s = 0.f, d = 0.f;
        if (tid < 200) {
            if (MODE == 0) {
                const float4 q4 = *(const float4*)&sd[(size_t)(b * 200 + tid) * 4];
                s = head ? q4.z : q4.x;
                d = head ? q4.w : q4.y;
            } else {
                const float2 q2 = *(const float2*)&sd[(size_t)(b * 200 + tid) * 2];
                s = q2.x; d = q2.y;
            }
        }
        src_l[tid] = s; dst_l[tid] = d;
    }
    __syncthreads();

    const int m = lane & 15, g = lane >> 4;

    for (int t = tA + w; t < tB; t += 4) {
        const int i0 = t * 16;
        const int isf = i0 + m;
        const float si = src_l[isf];

        f32x4 acc[F / 16];
        #pragma unroll
        for (int nt = 0; nt < F / 16; ++nt) acc[nt] = f32x4{0, 0, 0, 0};
        float sum = 0.f;

        #pragma unroll
        for (int ks = 0; ks < 7; ++ks) {
            const unsigned bits = (adjl[isf][ks] >> (g * 8)) & 0xffu;
            const float4 d0 = *(const float4*)&dst_l[ks * 32 + g * 8];
            const float4 d1 = *(const float4*)&dst_l[ks * 32 + g * 8 + 4];
            const float dvv[8] = {d0.x, d0.y, d0.z, d0.w, d1.x, d1.y, d1.z, d1.w};
            short8 af;
            #pragma unroll
            for (int u = 0; u < 8; ++u) {
                float v = si + dvv[u];
                v = fmaxf(v, ALPHA_ * v);                       // leaky-relu
                const float e = ((bits >> u) & 1u) ? v : NEGINF;
                const float p = __expf(fminf(e, 80.f));
                sum += p;
                af[u] = (short)f2b(p);
            }
            #pragma unroll
            for (int nt = 0; nt < F / 16; ++nt) {
                const short8 bf = *(const short8*)&hT[nt * 16 + m][ks * 32 + g * 8];
                acc[nt] = __builtin_amdgcn_mfma_f32_16x16x32_bf16(af, bf, acc[nt], 0, 0, 0);
            }
        }

        sum += __shfl_xor(sum, 16, 64);
        sum += __shfl_xor(sum, 32, 64);
        const float inv = 1.f / sum;           // inverse for row i0+m
        float invr[4];
        #pragma unroll
        for (int r = 0; r < 4; ++r) invr[r] = __shfl(inv, g * 4 + r, 64);

        #pragma unroll
        for (int nt = 0; nt < F / 16; ++nt) {
            #pragma unroll
            for (int r = 0; r < 4; ++r) {
                const int ii = i0 + g * 4 + r;
                if (ii < 200) {
                    float vv = acc[nt][r] * invr[r];
                    vv = (vv > 0.f) ? vv : expm1f(vv);
                    out[((size_t)b * 200 + ii) * 128 + outc0 + nt * 16 + m] = vv;
                }
            }
        }
    }
}

extern "C" void kernel_launch(void* const* d_in, const int* in_sizes, int n_in,
                              void* d_out, int out_size, void* d_ws, size_t ws_size,
                              hipStream_t stream)
{
    const float* x   = (const float*)d_in[0];
    const int*   adj = (const int*)  d_in[1];
    const float* W10 = (const float*)d_in[2];
    const float* a10 = (const float*)d_in[3];
    const float* W11 = (const float*)d_in[4];
    const float* a11 = (const float*)d_in[5];
    const float* W2  = (const float*)d_in[6];
    const float* a2  = (const float*)d_in[7];
    float* out = (float*)d_out;

    char* ws = (char*)d_ws;
    ushort*   HT   = (ushort*)  ws;                  // 7,340,032 B
    ushort*   WT1  = (ushort*) (ws + 7340032);       //    40,960 B
    ushort*   WT2  = (ushort*) (ws + 7380992);       //     8,192 B
    unsigned* adjb = (unsigned*)(ws + 7389184);      //     6,400 B
    float*    AC1  = (float*)  (ws + 7395584);       //     1,024 B
    float*    sd1  = (float*)  (ws + 7396608);       //   819,200 B
    float*    sd2  = (float*)  (ws + 8215808);       //   409,600 B  (8.63 MB)

    prep_kernel<<<200, 256, 0, stream>>>(adj, W10, W11, W2, a10, a11,
                                         adjb, WT1, WT2, AC1, HT);
    gemm_mfma<320, 320, 4><<<800, 256, 0, stream>>>(x, WT1, AC1, HT, sd1);
    attn_mfma<32, 0><<<1024, 256, 0, stream>>>(HT, adjb, sd1, out);
    gemm_mfma<64, 128, 2><<<800, 256, 0, stream>>>(out, WT2, a2, HT, sd2);
    attn_mfma<64, 1><<<1024, 256, 0, stream>>>(HT, adjb, sd2, out);
}

// Round 9
// 76.083 us; speedup vs baseline: 2.1253x; 1.1112x over previous
//
#include <hip/hip_runtime.h>
#include <cmath>

typedef __attribute__((ext_vector_type(8))) short short8;
typedef __attribute__((ext_vector_type(4))) float f32x4;

#define ALPHA_ 0.2f
#define NEGINF (-9.0e15f)

__device__ __forceinline__ ushort f2b(float f) {
    union { float f; unsigned u; } v; v.f = f;
    unsigned r = v.u + 0x7fffu + ((v.u >> 16) & 1u);
    return (ushort)(r >> 16);
}

// ---------------------------------------------------------------------------
// prep (grid 200 x 256)  [R6-verified]:
//  - adjb[i][0..7]: bitmask of adj row i (bit j%32 of dword j/32), j>=200 -> 0
//  - WT1[64][320], WT2[64][64]: transposed bf16 weights
//  - AC1[4][64]: layer-1 src/dst coefficient table (zero outside head range)
//  - HT pad columns [200,224) zeroed for all 256*64 feature rows
// ---------------------------------------------------------------------------
__global__ __launch_bounds__(256) void prep_kernel(
    const int* __restrict__ adj, const float* __restrict__ W10,
    const float* __restrict__ W11, const float* __restrict__ W2,
    const float* __restrict__ a10, const float* __restrict__ a11,
    unsigned* __restrict__ adjb, ushort* __restrict__ WT1,
    ushort* __restrict__ WT2, float* __restrict__ AC1,
    ushort* __restrict__ HT)
{
    const int bx = blockIdx.x, tid = threadIdx.x;
    if (tid < 8) {
        unsigned mask = 0;
        for (int u = 0; u < 32; ++u) {
            const int j = tid * 32 + u;
            if (j < 200 && adj[bx * 200 + j] > 0) mask |= (1u << u);
        }
        adjb[bx * 8 + tid] = mask;
    }
    const int gidx = bx * 256 + tid;                 // 0..51199
    if (gidx < 64 * 320) {
        const int n = gidx / 320, k = gidx % 320;
        WT1[gidx] = f2b(n < 32 ? W10[k * 32 + n] : W11[k * 32 + (n - 32)]);
    }
    if (gidx < 64 * 64) {
        const int n = gidx >> 6, k = gidx & 63;
        WT2[gidx] = f2b(W2[k * 64 + n]);
    }
    if (gidx < 256) {                                // AC1
        const int q = gidx >> 6, f = gidx & 63;
        float v = 0.f;
        if (q == 0 && f < 32)  v = a10[f];
        if (q == 1 && f < 32)  v = a10[32 + f];
        if (q == 2 && f >= 32) v = a11[f - 32];
        if (q == 3 && f >= 32) v = a11[f];           // a11[32 + (f-32)]
        AC1[gidx] = v;
    }
    if (gidx < 256 * 64 * 3) {                       // HT pad zero (3 x uint4 per row)
        const int c = gidx % 3, bf = gidx / 3;
        uint4 z{0, 0, 0, 0};
        *(uint4*)&HT[(size_t)bf * 224 + 200 + c * 8] = z;
    }
}

// ---------------------------------------------------------------------------
// gemm + fused src/dst dots  [R6-verified]:
//   HT[b][f][jpad224] (bf16) = X[51200 x K] @ W[K x 64]
//   SD[row][q] = sum_f acc[row][f] * AC[q][f]   (f32, from accumulators)
// ---------------------------------------------------------------------------
template<int K, int LDX, int NSD>
__global__ __launch_bounds__(256) void gemm_mfma(const float* __restrict__ X,
                                                 const ushort* __restrict__ WT,
                                                 const float* __restrict__ AC,
                                                 ushort* __restrict__ HT,
                                                 float* __restrict__ SD)
{
    constexpr int KP = K + 8;
    __shared__ __attribute__((aligned(16))) ushort wt_lds[64][KP];
    __shared__ __attribute__((aligned(16))) float acl[NSD * 64];
    const int tid = threadIdx.x;
    constexpr int CH = 64 * (K / 8);
    for (int c = tid; c < CH; c += 256) {
        int n = c / (K / 8), kc = (c % (K / 8)) * 8;
        *(short8*)&wt_lds[n][kc] = *(const short8*)&WT[n * K + kc];
    }
    if (tid < NSD * 64) acl[tid] = AC[tid];
    __syncthreads();

    const int lane = tid & 63, w = tid >> 6;
    const int m = lane & 15, g = lane >> 4;
    const int ko = g * 8;
    const size_t row = (size_t)blockIdx.x * 64 + w * 16 + m;

    f32x4 acc[4] = {{0,0,0,0},{0,0,0,0},{0,0,0,0},{0,0,0,0}};
    #pragma unroll
    for (int k0 = 0; k0 < K; k0 += 32) {
        const float4 x0 = *(const float4*)&X[row * LDX + k0 + ko];
        const float4 x1 = *(const float4*)&X[row * LDX + k0 + ko + 4];
        short8 a;
        a[0] = (short)f2b(x0.x); a[1] = (short)f2b(x0.y);
        a[2] = (short)f2b(x0.z); a[3] = (short)f2b(x0.w);
        a[4] = (short)f2b(x1.x); a[5] = (short)f2b(x1.y);
        a[6] = (short)f2b(x1.z); a[7] = (short)f2b(x1.w);
        #pragma unroll
        for (int nt = 0; nt < 4; ++nt) {
            const short8 bfr = *(const short8*)&wt_lds[nt * 16 + m][k0 + ko];
            acc[nt] = __builtin_amdgcn_mfma_f32_16x16x32_bf16(a, bfr, acc[nt], 0, 0, 0);
        }
    }

    // HT store (bf16 packed), rows rb..rb+3 (4 | 200 -> never straddles batch)
    const unsigned rb = (unsigned)blockIdx.x * 64 + w * 16 + g * 4;
    const unsigned bt = rb / 200u;
    const unsigned ir = rb - bt * 200u;
    #pragma unroll
    for (int nt = 0; nt < 4; ++nt) {
        uint2 pk;
        pk.x = (unsigned)f2b(acc[nt][0]) | ((unsigned)f2b(acc[nt][1]) << 16);
        pk.y = (unsigned)f2b(acc[nt][2]) | ((unsigned)f2b(acc[nt][3]) << 16);
        *(uint2*)&HT[((size_t)bt * 64 + nt * 16 + m) * 224 + ir] = pk;
    }

    // fused src/dst dots from f32 accumulators
    float sdv[NSD][4];
    #pragma unroll
    for (int q = 0; q < NSD; ++q)
        #pragma unroll
        for (int r = 0; r < 4; ++r) {
            float s = 0.f;
            #pragma unroll
            for (int nt = 0; nt < 4; ++nt) s += acc[nt][r] * acl[q * 64 + nt * 16 + m];
            sdv[q][r] = s;
        }
    #pragma unroll
    for (int q = 0; q < NSD; ++q)
        #pragma unroll
        for (int r = 0; r < 4; ++r) {
            float s = sdv[q][r];
            s += __shfl_xor(s, 1, 64); s += __shfl_xor(s, 2, 64);
            s += __shfl_xor(s, 4, 64); s += __shfl_xor(s, 8, 64);
            sdv[q][r] = s;
        }
    if (m == 0) {
        #pragma unroll
        for (int r = 0; r < 4; ++r) {
            if (NSD == 4) {
                float4 o; o.x = sdv[0][r]; o.y = sdv[1][r];
                o.z = sdv[2][r]; o.w = sdv[3][r];
                *(float4*)&SD[(size_t)(rb + r) * 4] = o;
            } else {
                float2 o; o.x = sdv[0][r]; o.y = sdv[1][r];
                *(float2*)&SD[(size_t)(rb + r) * 2] = o;
            }
        }
    }
}

// ---------------------------------------------------------------------------
// Fused GAT attention [R6-verified core], single-pass no-max softmax,
// ks-outer PV.  New this round (value-identical):
//   - bijective XCD swizzle of blockIdx (1024 = 8 x 128 exactly)
//   - s_setprio(1) around the MFMA cluster (scheduler hint)
// MODE 0: sbx = ((b*2+head)*2+sub), sub {0,1}: tiles 0..6 / 7..12. F=32.
// MODE 1: sbx = b*4+sub, sub {0..3}: tiles {0-3,4-6,7-9,10-12}. F=64.
// ---------------------------------------------------------------------------
template<int F, int MODE>
__global__ __launch_bounds__(256) void attn_mfma(const ushort* __restrict__ HT,
                                                 const unsigned* __restrict__ adjb,
                                                 const float* __restrict__ sd,
                                                 float* __restrict__ out)
{
    __shared__ __attribute__((aligned(16))) ushort hT[F][232];
    __shared__ __attribute__((aligned(16))) float src_l[224];
    __shared__ __attribute__((aligned(16))) float dst_l[224];
    __shared__ unsigned adjl[208][9];   // pad 9 -> conflict-free row reads

    const int tid = threadIdx.x;
    const int lane = tid & 63, w = tid >> 6;
    // XCD swizzle: grid is exactly 1024 = 8 XCD * 128; transpose mapping is
    // bijective and value-identical (pure re-labeling of blocks).
    const int bx = ((blockIdx.x & 7) << 7) | (blockIdx.x >> 3);
    int b, hoff, outc0, head, tA, tB;
    if (MODE == 0) {
        b = bx >> 2; head = (bx >> 1) & 1; const int sub = bx & 1;
        hoff = head * 32; outc0 = head * 32;
        tA = sub ? 7 : 0; tB = sub ? 13 : 7;
    } else {
        b = bx >> 2; head = 0; const int sub = bx & 3;
        hoff = 0; outc0 = 64;
        tA = (sub == 0) ? 0 : 4 + (sub - 1) * 3;
        tB = (sub == 0) ? 4 : tA + 3;
    }

    // stage hT (coalesced short8)
    const ushort* hg = HT + ((size_t)b * 64 + hoff) * 224;
    for (int idx = tid; idx < F * 28; idx += 256) {
        const int f = idx / 28, c = idx % 28;
        *(short8*)&hT[f][c * 8] = *(const short8*)&hg[(size_t)f * 224 + c * 8];
    }
    // stage adj bitmasks (rows 200..207 zero; col 8 = pad, unwritten)
    for (int idx = tid; idx < 208 * 8; idx += 256) {
        const int i = idx >> 3, c = idx & 7;
        adjl[i][c] = (i < 200) ? adjb[i * 8 + c] : 0u;
    }
    // stage src/dst (f32 from fused gemm epilogue tables)
    if (tid < 224) {
        float s = 0.f, d = 0.f;
        if (tid < 200) {
            if (MODE == 0) {
                const float4 q4 = *(const float4*)&sd[(size_t)(b * 200 + tid) * 4];
                s = head ? q4.z : q4.x;
                d = head ? q4.w : q4.y;
            } else {
                const float2 q2 = *(const float2*)&sd[(size_t)(b * 200 + tid) * 2];
                s = q2.x; d = q2.y;
            }
        }
        src_l[tid] = s; dst_l[tid] = d;
    }
    __syncthreads();

    const int m = lane & 15, g = lane >> 4;

    for (int t = tA + w; t < tB; t += 4) {
        const int i0 = t * 16;
        const int isf = i0 + m;
        const float si = src_l[isf];

        f32x4 acc[F / 16];
        #pragma unroll
        for (int nt = 0; nt < F / 16; ++nt) acc[nt] = f32x4{0, 0, 0, 0};
        float sum = 0.f;

        #pragma unroll
        for (int ks = 0; ks < 7; ++ks) {
            const unsigned bits = (adjl[isf][ks] >> (g * 8)) & 0xffu;
            const float4 d0 = *(const float4*)&dst_l[ks * 32 + g * 8];
            const float4 d1 = *(const float4*)&dst_l[ks * 32 + g * 8 + 4];
            const float dvv[8] = {d0.x, d0.y, d0.z, d0.w, d1.x, d1.y, d1.z, d1.w};
            short8 af;
            #pragma unroll
            for (int u = 0; u < 8; ++u) {
                float v = si + dvv[u];
                v = fmaxf(v, ALPHA_ * v);                       // leaky-relu
                const float e = ((bits >> u) & 1u) ? v : NEGINF;
                const float p = __expf(fminf(e, 80.f));
                sum += p;
                af[u] = (short)f2b(p);
            }
            __builtin_amdgcn_s_setprio(1);
            #pragma unroll
            for (int nt = 0; nt < F / 16; ++nt) {
                const short8 bf = *(const short8*)&hT[nt * 16 + m][ks * 32 + g * 8];
                acc[nt] = __builtin_amdgcn_mfma_f32_16x16x32_bf16(af, bf, acc[nt], 0, 0, 0);
            }
            __builtin_amdgcn_s_setprio(0);
        }

        sum += __shfl_xor(sum, 16, 64);
        sum += __shfl_xor(sum, 32, 64);
        const float inv = 1.f / sum;           // inverse for row i0+m
        float invr[4];
        #pragma unroll
        for (int r = 0; r < 4; ++r) invr[r] = __shfl(inv, g * 4 + r, 64);

        #pragma unroll
        for (int nt = 0; nt < F / 16; ++nt) {
            #pragma unroll
            for (int r = 0; r < 4; ++r) {
                const int ii = i0 + g * 4 + r;
                if (ii < 200) {
                    float vv = acc[nt][r] * invr[r];
                    vv = (vv > 0.f) ? vv : expm1f(vv);          // accurate ELU
                    out[((size_t)b * 200 + ii) * 128 + outc0 + nt * 16 + m] = vv;
                }
            }
        }
    }
}

extern "C" void kernel_launch(void* const* d_in, const int* in_sizes, int n_in,
                              void* d_out, int out_size, void* d_ws, size_t ws_size,
                              hipStream_t stream)
{
    const float* x   = (const float*)d_in[0];
    const int*   adj = (const int*)  d_in[1];
    const float* W10 = (const float*)d_in[2];
    const float* a10 = (const float*)d_in[3];
    const float* W11 = (const float*)d_in[4];
    const float* a11 = (const float*)d_in[5];
    const float* W2  = (const float*)d_in[6];
    const float* a2  = (const float*)d_in[7];
    float* out = (float*)d_out;

    char* ws = (char*)d_ws;
    ushort*   HT   = (ushort*)  ws;                  // 7,340,032 B
    ushort*   WT1  = (ushort*) (ws + 7340032);       //    40,960 B
    ushort*   WT2  = (ushort*) (ws + 7380992);       //     8,192 B
    unsigned* adjb = (unsigned*)(ws + 7389184);      //     6,400 B
    float*    AC1  = (float*)  (ws + 7395584);       //     1,024 B
    float*    sd1  = (float*)  (ws + 7396608);       //   819,200 B
    float*    sd2  = (float*)  (ws + 8215808);       //   409,600 B  (8.63 MB)

    prep_kernel<<<200, 256, 0, stream>>>(adj, W10, W11, W2, a10, a11,
                                         adjb, WT1, WT2, AC1, HT);
    gemm_mfma<320, 320, 4><<<800, 256, 0, stream>>>(x, WT1, AC1, HT, sd1);
    attn_mfma<32, 0><<<1024, 256, 0, stream>>>(HT, adjb, sd1, out);
    gemm_mfma<64, 128, 2><<<800, 256, 0, stream>>>(out, WT2, a2, HT, sd2);
    attn_mfma<64, 1><<<1024, 256, 0, stream>>>(HT, adjb, sd2, out);
}